// Round 2
// baseline (275.073 us; speedup 1.0000x reference)
//
#include <hip/hip_runtime.h>
#include <math.h>

#define BB 128
#define TT_ 64
#define NN 81
#define MM 128
#define GG 512      // 4*M
#define TN 5184     // T*N
#define TCH 8       // timesteps per block in k2
#define NBLK2 (BB * (TT_ / TCH))   // 1024
#define SC_ 2.8853900817779268f    // 2*log2(e): exp2(SC*z) = e^{2z}

typedef float f32x4 __attribute__((ext_vector_type(4)));

__device__ __forceinline__ float sigmoidf_(float x) {
    return 1.0f / (1.0f + __expf(-x));
}
__device__ __forceinline__ float fast_tanh(float x) {
    float e = __expf(2.0f * x);
    return 1.0f - 2.0f / (e + 1.0f);
}

// ---------------- kernel 1: 512 blocks (4 per batch).
// Each block: U'[b][i][k] = SC*(sum_t X[t][i]*Ue_w[t][k] + Ue_b[k]) for k in q*16..+16.
// q==0 also does hb = h0@U_lstm + b_lstm.
__global__ __launch_bounds__(256) void k1_prep(
    const float* __restrict__ X, const float* __restrict__ h0,
    const float* __restrict__ U_lstm, const float* __restrict__ b_lstm,
    const float* __restrict__ Ue_w, const float* __restrict__ Ue_b,
    float* __restrict__ ws_hb, float* __restrict__ ws_U)
{
    __shared__ float Xl[TN];
    __shared__ float sUe[64 * 16];
    __shared__ float h0l[MM];

    int blk = blockIdx.x;
    int b = blk >> 2;
    int q = blk & 3;
    int tid = threadIdx.x;

    for (int p = tid; p < TN; p += 256) Xl[p] = X[b * TN + p];
    for (int p = tid; p < 1024; p += 256) {
        int t = p >> 4, kl = p & 15;
        sUe[p] = Ue_w[t * TT_ + q * 16 + kl];
    }
    if (q == 0 && tid < MM) h0l[tid] = h0[b * MM + tid];
    __syncthreads();

    if (q == 0) {
        float2 bl = ((const float2*)b_lstm)[tid];
        float a0 = bl.x, a1 = bl.y;
        for (int j = 0; j < MM; ++j) {
            float h = h0l[j];
            float2 w = ((const float2*)&U_lstm[j * GG])[tid];
            a0 += h * w.x;
            a1 += h * w.y;
        }
        ((float2*)&ws_hb[b * GG])[tid] = make_float2(a0, a1);
    }

    int kl = tid & 15;
    int k  = q * 16 + kl;
    int ir = tid >> 4;
    float ueb = Ue_b[k];
#pragma unroll
    for (int pass = 0; pass < 6; ++pass) {
        int i = pass * 16 + ir;
        if (i < NN) {
            float acc = ueb;
#pragma unroll 8
            for (int t = 0; t < TT_; ++t)
                acc += Xl[t * NN + i] * sUe[t * 16 + kl];
            ws_U[b * TN + i * 64 + k] = acc * SC_;   // pre-scaled
        }
    }
}

// ---------------- kernel 2: gates -> hc -> A' -> scores -> alpha (no epilogue)
__global__ __launch_bounds__(256, 4) void k2_attn(
    const float* __restrict__ X, const float* __restrict__ s0,
    const float* __restrict__ W_lstm,
    const float* __restrict__ We_w, const float* __restrict__ We_b,
    const float* __restrict__ ve_w, const float* __restrict__ ve_b,
    const float* __restrict__ ws_hb, const float* __restrict__ ws_U,
    float* __restrict__ ws_al)
{
    __shared__ alignas(16) float sXct[NN * TCH];   // [n][tt] transposed X chunk (648)
    __shared__ float sU[NN * 65];                  // U' pre-scaled, padded (5265)
    __shared__ float sHc[TCH * 256];               // [tt][ h | c ] (2048)
    __shared__ float sA[TCH * 65];                 // A' pre-scaled, padded (520)
    __shared__ float sVe[TT_];

    int blk = blockIdx.x;
    int b  = blk >> 3;
    int tc = blk & 7;
    int t0 = tc * TCH;
    int tid = threadIdx.x;
    int u    = tid & 127;
    int half = tid >> 7;        // tt block: half*4 .. half*4+3
    float veb = ve_b[0];

    // ---- stage: issue all independent global loads up front
    float hb0 = ws_hb[b * GG + u];
    float hb1 = ws_hb[b * GG + 128 + u];
    float hb2 = ws_hb[b * GG + 256 + u];
    float hb3 = ws_hb[b * GG + 384 + u];
    float s0v = s0[b * MM + u];

    for (int p = tid; p < NN * TCH; p += 256) {
        float v = X[b * TN + t0 * NN + p];
        int tt = p / NN, np = p - tt * NN;
        sXct[np * TCH + tt] = v;
    }
    for (int p = tid; p < TN; p += 256) {
        int i = p >> 6, k = p & 63;
        sU[i * 65 + k] = ws_U[b * TN + p];
    }
    if (tid < TT_) sVe[tid] = ve_w[tid];
    __syncthreads();                                  // B1

    // ---- phase 1: gates in registers. thread owns unit u, tts half*4..+3, all 4 gates.
    float acc[4][4];
#pragma unroll
    for (int r = 0; r < 4; ++r) {
        acc[r][0] = hb0; acc[r][1] = hb1; acc[r][2] = hb2; acc[r][3] = hb3;
    }
    {
        const float* Wl = &W_lstm[u];
        for (int n = 0; n < NN; ++n) {
            float w0 = Wl[n * GG];
            float w1 = Wl[n * GG + 128];
            float w2 = Wl[n * GG + 256];
            float w3 = Wl[n * GG + 384];
            float4 xv = *(const float4*)&sXct[n * TCH + 4 * half];
            acc[0][0] += xv.x * w0; acc[0][1] += xv.x * w1; acc[0][2] += xv.x * w2; acc[0][3] += xv.x * w3;
            acc[1][0] += xv.y * w0; acc[1][1] += xv.y * w1; acc[1][2] += xv.y * w2; acc[1][3] += xv.y * w3;
            acc[2][0] += xv.z * w0; acc[2][1] += xv.z * w1; acc[2][2] += xv.z * w2; acc[2][3] += xv.z * w3;
            acc[3][0] += xv.w * w0; acc[3][1] += xv.w * w1; acc[3][2] += xv.w * w2; acc[3][3] += xv.w * w3;
        }
    }
    // ---- activations in registers -> sHc
#pragma unroll
    for (int r = 0; r < 4; ++r) {
        int tt = 4 * half + r;
        float gi = sigmoidf_(acc[r][0]);
        float gf = sigmoidf_(acc[r][1]);
        float gg = fast_tanh(acc[r][2]);
        float go = sigmoidf_(acc[r][3]);
        float c  = gf * s0v + gi * gg;
        float h  = go * fast_tanh(c);
        sHc[tt * 256 + u]       = h;
        sHc[tt * 256 + 128 + u] = c;
    }
    __syncthreads();                                  // B2

    // ---- wave-local from here to alpha. wave wv owns tt = wv and wv+4.
    int wv = tid >> 6;
    int l  = tid & 63;

    // phase 2: A'[tt][k] = SC*(sum_j hc[tt][j]*We_w[j][k] + We_b[k]), k = l
    {
        float a0 = We_b[l], a1 = a0;
        const float* Wep = &We_w[l];
        for (int j = 0; j < 256; ++j) {
            float w  = Wep[j * TT_];
            a0 += sHc[wv * 256 + j]       * w;
            a1 += sHc[(wv + 4) * 256 + j] * w;
        }
        sA[wv * 65 + l]       = a0 * SC_;
        sA[(wv + 4) * 65 + l] = a1 * SC_;
    }
    // sumVe via wave reduce
    float sumVe;
    {
        float sv = sVe[l];
        sumVe = sv;
        for (int d = 32; d >= 1; d >>= 1) sumVe += __shfl_xor(sumVe, d, 64);
    }

    // phase 3 + softmax fused, per owned tt; alpha written straight to global
#pragma unroll
    for (int hh = 0; hh < 2; ++hh) {
        int tt = wv + hh * 4;
        const float* Ar = &sA[tt * 65];
        float sc0, sc1;
        {
            const float* Ur = &sU[l * 65];
            float a2 = 0.f;
#pragma unroll 8
            for (int k = 0; k < TT_; ++k) {
                float s = Ar[k] + Ur[k];
                float e = exp2f(s);
                float r2 = __builtin_amdgcn_rcpf(e + 1.0f);
                a2 = fmaf(sVe[k], r2, a2);
            }
            sc0 = sumVe - 2.0f * a2 + veb;
        }
        bool v2 = (l + 64 < NN);
        if (v2) {
            const float* Ur = &sU[(l + 64) * 65];
            float a2 = 0.f;
#pragma unroll 8
            for (int k = 0; k < TT_; ++k) {
                float s = Ar[k] + Ur[k];
                float e = exp2f(s);
                float r2 = __builtin_amdgcn_rcpf(e + 1.0f);
                a2 = fmaf(sVe[k], r2, a2);
            }
            sc1 = sumVe - 2.0f * a2 + veb;
        } else {
            sc1 = -1e30f;
        }
        // softmax over the 81 scores of row tt
        float mx = fmaxf(sc0, sc1);
        for (int d = 32; d >= 1; d >>= 1) mx = fmaxf(mx, __shfl_xor(mx, d, 64));
        float ea = __expf(sc0 - mx);
        float eb = v2 ? __expf(sc1 - mx) : 0.f;
        float s = ea + eb;
        for (int d = 32; d >= 1; d >>= 1) s += __shfl_xor(s, d, 64);
        float inv = 1.f / s;
        float* alr = &ws_al[((size_t)b * TT_ + (t0 + tt)) * NN];
        alr[l] = ea * inv;
        if (v2) alr[l + 64] = eb * inv;
    }
}

// ---------------- kernel 3: out[t,b,:, :] = X[b,:,:] * alpha[b,t,i]  (pure write-BW)
#define TPB3 8    // timesteps per k3 block; grid = BB * (TT_/TPB3) = 1024
__global__ __launch_bounds__(256) void k3_out(
    const float* __restrict__ X, const float* __restrict__ ws_al,
    float* __restrict__ out)
{
    __shared__ float sAl[TPB3 * NN];   // 8 alpha rows (648 floats)
    int blk = blockIdx.x;
    int b  = blk >> 3;
    int tg = blk & 7;
    int t0 = tg * TPB3;
    int tid = threadIdx.x;

    for (int p = tid; p < TPB3 * NN; p += 256)
        sAl[p] = ws_al[((size_t)b * TT_ + t0) * NN + p];
    __syncthreads();

    const f32x4* Xb4 = (const f32x4*)(X + (size_t)b * TN);
    f32x4* out4 = (f32x4*)out;

    for (int p = tid; p < TN / 4; p += 256) {
        f32x4 x4 = Xb4[p];
        int j = p * 4;
        int i0 = j % NN;
        int i1 = i0 + 1; if (i1 == NN) i1 = 0;
        int i2 = i1 + 1; if (i2 == NN) i2 = 0;
        int i3 = i2 + 1; if (i3 == NN) i3 = 0;
#pragma unroll
        for (int tt = 0; tt < TPB3; ++tt) {
            const float* al = &sAl[tt * NN];
            f32x4 o;
            o.x = x4.x * al[i0];
            o.y = x4.y * al[i1];
            o.z = x4.z * al[i2];
            o.w = x4.w * al[i3];
            __builtin_nontemporal_store(o, out4 + ((size_t)(t0 + tt) * BB + b) * (TN / 4) + p);
        }
    }
}

extern "C" void kernel_launch(void* const* d_in, const int* in_sizes, int n_in,
                              void* d_out, int out_size, void* d_ws, size_t ws_size,
                              hipStream_t stream) {
    const float* X      = (const float*)d_in[0];
    const float* h0     = (const float*)d_in[1];
    const float* s0     = (const float*)d_in[2];
    const float* W_lstm = (const float*)d_in[3];
    const float* U_lstm = (const float*)d_in[4];
    const float* b_lstm = (const float*)d_in[5];
    const float* We_w   = (const float*)d_in[6];
    const float* We_b   = (const float*)d_in[7];
    const float* Ue_w   = (const float*)d_in[8];
    const float* Ue_b   = (const float*)d_in[9];
    const float* ve_w   = (const float*)d_in[10];
    const float* ve_b   = (const float*)d_in[11];
    float* out = (float*)d_out;

    float* ws    = (float*)d_ws;
    float* ws_hb = ws;                        // B*512 floats
    float* ws_U  = ws + BB * GG;              // B*5184 floats
    float* ws_al = ws + BB * GG + BB * TN;    // B*T*81 floats (alpha)

    k1_prep<<<BB * 4, 256, 0, stream>>>(X, h0, U_lstm, b_lstm, Ue_w, Ue_b, ws_hb, ws_U);
    k2_attn<<<NBLK2, 256, 0, stream>>>(X, s0, W_lstm, We_w, We_b, ve_w, ve_b,
                                       ws_hb, ws_U, ws_al);
    k3_out<<<BB * (TT_ / TPB3), 256, 0, stream>>>(X, ws_al, out);
}

// Round 3
// 256.973 us; speedup vs baseline: 1.0704x; 1.0704x over previous
//
#include <hip/hip_runtime.h>
#include <math.h>

#define BB 128
#define TT_ 64
#define NN 81
#define MM 128
#define GG 512      // 4*M
#define TN 5184     // T*N
#define TCH 8       // timesteps per block in k2
#define NBLK2 (BB * (TT_ / TCH))   // 1024
#define SC_ 2.8853900817779268f    // 2*log2(e): exp2(SC*z) = e^{2z}

typedef float f32x4 __attribute__((ext_vector_type(4)));

__device__ __forceinline__ float sigmoidf_(float x) {
    return 1.0f / (1.0f + __expf(-x));
}
__device__ __forceinline__ float fast_tanh(float x) {
    float e = __expf(2.0f * x);
    return 1.0f - 2.0f / (e + 1.0f);
}

// ---------------- kernel 1: 512 blocks (4 per batch).
// Each block: U'[b][i][k] = SC*(sum_t X[t][i]*Ue_w[t][k] + Ue_b[k]) for k in q*16..+16.
// q==0 also does hb = h0@U_lstm + b_lstm.
__global__ __launch_bounds__(256) void k1_prep(
    const float* __restrict__ X, const float* __restrict__ h0,
    const float* __restrict__ U_lstm, const float* __restrict__ b_lstm,
    const float* __restrict__ Ue_w, const float* __restrict__ Ue_b,
    float* __restrict__ ws_hb, float* __restrict__ ws_U)
{
    __shared__ float Xl[TN];
    __shared__ float sUe[64 * 16];
    __shared__ float h0l[MM];

    int blk = blockIdx.x;
    int b = blk >> 2;
    int q = blk & 3;
    int tid = threadIdx.x;

    for (int p = tid; p < TN; p += 256) Xl[p] = X[b * TN + p];
    for (int p = tid; p < 1024; p += 256) {
        int t = p >> 4, kl = p & 15;
        sUe[p] = Ue_w[t * TT_ + q * 16 + kl];
    }
    if (q == 0 && tid < MM) h0l[tid] = h0[b * MM + tid];
    __syncthreads();

    if (q == 0) {
        float2 bl = ((const float2*)b_lstm)[tid];
        float a0 = bl.x, a1 = bl.y;
        for (int j = 0; j < MM; ++j) {
            float h = h0l[j];
            float2 w = ((const float2*)&U_lstm[j * GG])[tid];
            a0 += h * w.x;
            a1 += h * w.y;
        }
        ((float2*)&ws_hb[b * GG])[tid] = make_float2(a0, a1);
    }

    int kl = tid & 15;
    int k  = q * 16 + kl;
    int ir = tid >> 4;
    float ueb = Ue_b[k];
#pragma unroll
    for (int pass = 0; pass < 6; ++pass) {
        int i = pass * 16 + ir;
        if (i < NN) {
            float acc = ueb;
#pragma unroll 8
            for (int t = 0; t < TT_; ++t)
                acc += Xl[t * NN + i] * sUe[t * 16 + kl];
            ws_U[b * TN + i * 64 + k] = acc * SC_;   // pre-scaled
        }
    }
}

// ---------------- kernel 2: fused pipeline, vectorized nt epilogue
__global__ __launch_bounds__(256, 4) void k2_main(
    const float* __restrict__ X, const float* __restrict__ s0,
    const float* __restrict__ W_lstm,
    const float* __restrict__ We_w, const float* __restrict__ We_b,
    const float* __restrict__ ve_w, const float* __restrict__ ve_b,
    const float* __restrict__ ws_hb, const float* __restrict__ ws_U,
    float* __restrict__ out)
{
    __shared__ alignas(16) float sXct[NN * TCH];   // [n][tt] transposed X chunk (648)
    __shared__ float sU[NN * 65];                  // U' pre-scaled, padded (5265)
    __shared__ float sHc[TCH * 256];               // [tt][ h | c ] (2048)
    __shared__ float sA[TCH * 65];                 // A' pre-scaled, padded (520)
    __shared__ float sSc[TCH * NN];                // alpha (648)
    __shared__ float sVe[TT_];

    int blk = blockIdx.x;
    int b  = blk >> 3;
    int tc = blk & 7;
    int t0 = tc * TCH;
    int tid = threadIdx.x;
    int u    = tid & 127;
    int half = tid >> 7;        // tt block: half*4 .. half*4+3
    float veb = ve_b[0];

    // ---- stage: issue all independent global loads up front
    float hb0 = ws_hb[b * GG + u];
    float hb1 = ws_hb[b * GG + 128 + u];
    float hb2 = ws_hb[b * GG + 256 + u];
    float hb3 = ws_hb[b * GG + 384 + u];
    float s0v = s0[b * MM + u];

    for (int p = tid; p < NN * TCH; p += 256) {
        float v = X[b * TN + t0 * NN + p];
        int tt = p / NN, np = p - tt * NN;
        sXct[np * TCH + tt] = v;
    }
    for (int p = tid; p < TN; p += 256) {
        int i = p >> 6, k = p & 63;
        sU[i * 65 + k] = ws_U[b * TN + p];
    }
    if (tid < TT_) sVe[tid] = ve_w[tid];
    __syncthreads();                                  // B1

    // ---- phase 1: gates in registers. thread owns unit u, tts half*4..+3, all 4 gates.
    float acc[4][4];
#pragma unroll
    for (int r = 0; r < 4; ++r) {
        acc[r][0] = hb0; acc[r][1] = hb1; acc[r][2] = hb2; acc[r][3] = hb3;
    }
    {
        const float* Wl = &W_lstm[u];
        for (int n = 0; n < NN; ++n) {
            float w0 = Wl[n * GG];
            float w1 = Wl[n * GG + 128];
            float w2 = Wl[n * GG + 256];
            float w3 = Wl[n * GG + 384];
            float4 xv = *(const float4*)&sXct[n * TCH + 4 * half];
            acc[0][0] += xv.x * w0; acc[0][1] += xv.x * w1; acc[0][2] += xv.x * w2; acc[0][3] += xv.x * w3;
            acc[1][0] += xv.y * w0; acc[1][1] += xv.y * w1; acc[1][2] += xv.y * w2; acc[1][3] += xv.y * w3;
            acc[2][0] += xv.z * w0; acc[2][1] += xv.z * w1; acc[2][2] += xv.z * w2; acc[2][3] += xv.z * w3;
            acc[3][0] += xv.w * w0; acc[3][1] += xv.w * w1; acc[3][2] += xv.w * w2; acc[3][3] += xv.w * w3;
        }
    }
    // ---- activations in registers -> sHc
#pragma unroll
    for (int r = 0; r < 4; ++r) {
        int tt = 4 * half + r;
        float gi = sigmoidf_(acc[r][0]);
        float gf = sigmoidf_(acc[r][1]);
        float gg = fast_tanh(acc[r][2]);
        float go = sigmoidf_(acc[r][3]);
        float c  = gf * s0v + gi * gg;
        float h  = go * fast_tanh(c);
        sHc[tt * 256 + u]       = h;
        sHc[tt * 256 + 128 + u] = c;
    }
    __syncthreads();                                  // B2

    // ---- wave-local from here to alpha. wave wv owns tt = wv and wv+4.
    int wv = tid >> 6;
    int l  = tid & 63;

    // phase 2: A'[tt][k] = SC*(sum_j hc[tt][j]*We_w[j][k] + We_b[k]), k = l
    {
        float a0 = We_b[l], a1 = a0;
        const float* Wep = &We_w[l];
        for (int j = 0; j < 256; ++j) {
            float w  = Wep[j * TT_];
            a0 += sHc[wv * 256 + j]       * w;
            a1 += sHc[(wv + 4) * 256 + j] * w;
        }
        sA[wv * 65 + l]       = a0 * SC_;
        sA[(wv + 4) * 65 + l] = a1 * SC_;
    }
    // sumVe via wave reduce
    float sumVe;
    {
        float sv = sVe[l];
        sumVe = sv;
        for (int d = 32; d >= 1; d >>= 1) sumVe += __shfl_xor(sumVe, d, 64);
    }

    // phase 3 + softmax fused, per owned tt
#pragma unroll
    for (int hh = 0; hh < 2; ++hh) {
        int tt = wv + hh * 4;
        const float* Ar = &sA[tt * 65];
        float sc0, sc1;
        {
            const float* Ur = &sU[l * 65];
            float a2 = 0.f;
#pragma unroll 8
            for (int k = 0; k < TT_; ++k) {
                float s = Ar[k] + Ur[k];
                float e = exp2f(s);
                float r2 = __builtin_amdgcn_rcpf(e + 1.0f);
                a2 = fmaf(sVe[k], r2, a2);
            }
            sc0 = sumVe - 2.0f * a2 + veb;
        }
        bool v2 = (l + 64 < NN);
        if (v2) {
            const float* Ur = &sU[(l + 64) * 65];
            float a2 = 0.f;
#pragma unroll 8
            for (int k = 0; k < TT_; ++k) {
                float s = Ar[k] + Ur[k];
                float e = exp2f(s);
                float r2 = __builtin_amdgcn_rcpf(e + 1.0f);
                a2 = fmaf(sVe[k], r2, a2);
            }
            sc1 = sumVe - 2.0f * a2 + veb;
        } else {
            sc1 = -1e30f;
        }
        // softmax over the 81 scores of row tt
        float mx = fmaxf(sc0, sc1);
        for (int d = 32; d >= 1; d >>= 1) mx = fmaxf(mx, __shfl_xor(mx, d, 64));
        float ea = __expf(sc0 - mx);
        float eb = v2 ? __expf(sc1 - mx) : 0.f;
        float s = ea + eb;
        for (int d = 32; d >= 1; d >>= 1) s += __shfl_xor(s, d, 64);
        float inv = 1.f / s;
        sSc[tt * NN + l] = ea * inv;
        if (v2) sSc[tt * NN + l + 64] = eb * inv;
    }
    __syncthreads();                                  // B3

    // ---- phase 4: out[t0+tt, b, t2, i] = X[b, t2, i] * alpha[tt][i]
    // f32x4 loads of X + nontemporal f32x4 stores (write-once data, skip L2).
    {
        const f32x4* Xb4 = (const f32x4*)(X + (size_t)b * TN);
        f32x4* out4 = (f32x4*)out;
        for (int p = tid; p < TN / 4; p += 256) {
            f32x4 x4 = Xb4[p];
            int j = p * 4;
            int i0 = j % NN;
            int i1 = i0 + 1; if (i1 == NN) i1 = 0;
            int i2 = i1 + 1; if (i2 == NN) i2 = 0;
            int i3 = i2 + 1; if (i3 == NN) i3 = 0;
#pragma unroll
            for (int tt = 0; tt < TCH; ++tt) {
                const float* al = &sSc[tt * NN];
                f32x4 o;
                o.x = x4.x * al[i0];
                o.y = x4.y * al[i1];
                o.z = x4.z * al[i2];
                o.w = x4.w * al[i3];
                __builtin_nontemporal_store(o, out4 + ((size_t)(t0 + tt) * BB + b) * (TN / 4) + p);
            }
        }
    }
}

extern "C" void kernel_launch(void* const* d_in, const int* in_sizes, int n_in,
                              void* d_out, int out_size, void* d_ws, size_t ws_size,
                              hipStream_t stream) {
    const float* X      = (const float*)d_in[0];
    const float* h0     = (const float*)d_in[1];
    const float* s0     = (const float*)d_in[2];
    const float* W_lstm = (const float*)d_in[3];
    const float* U_lstm = (const float*)d_in[4];
    const float* b_lstm = (const float*)d_in[5];
    const float* We_w   = (const float*)d_in[6];
    const float* We_b   = (const float*)d_in[7];
    const float* Ue_w   = (const float*)d_in[8];
    const float* Ue_b   = (const float*)d_in[9];
    const float* ve_w   = (const float*)d_in[10];
    const float* ve_b   = (const float*)d_in[11];
    float* out = (float*)d_out;

    float* ws    = (float*)d_ws;
    float* ws_hb = ws;                  // B*512 floats
    float* ws_U  = ws + BB * GG;        // B*5184 floats

    k1_prep<<<BB * 4, 256, 0, stream>>>(X, h0, U_lstm, b_lstm, Ue_w, Ue_b, ws_hb, ws_U);
    k2_main<<<NBLK2, 256, 0, stream>>>(X, s0, W_lstm, We_w, We_b, ve_w, ve_b,
                                       ws_hb, ws_U, out);
}

// Round 4
// 255.527 us; speedup vs baseline: 1.0765x; 1.0057x over previous
//
#include <hip/hip_runtime.h>
#include <math.h>

#define BB 128
#define TT_ 64
#define NN 81
#define MM 128
#define GG 512      // 4*M
#define TN 5184     // T*N
#define TCH 8       // timesteps per block in k2
#define NBLK2 (BB * (TT_ / TCH))   // 1024
#define SC_ 2.8853900817779268f    // 2*log2(e): exp2(SC*z) = e^{2z}

typedef float f32x4 __attribute__((ext_vector_type(4)));

__device__ __forceinline__ float sigmoidf_(float x) {
    return 1.0f / (1.0f + __expf(-x));
}
__device__ __forceinline__ float fast_tanh(float x) {
    float e = __expf(2.0f * x);
    return 1.0f - 2.0f / (e + 1.0f);
}

// ---------------- kernel 1: 512 blocks (4 per batch).
// Each block: eU[b][i][k] = exp2(SC*(sum_t X[t][i]*Ue_w[t][k] + Ue_b[k])) for k in q*16..+16.
// q==0 also does hb = h0@U_lstm + b_lstm.
__global__ __launch_bounds__(256) void k1_prep(
    const float* __restrict__ X, const float* __restrict__ h0,
    const float* __restrict__ U_lstm, const float* __restrict__ b_lstm,
    const float* __restrict__ Ue_w, const float* __restrict__ Ue_b,
    float* __restrict__ ws_hb, float* __restrict__ ws_U)
{
    __shared__ float Xl[TN];
    __shared__ float sUe[64 * 16];
    __shared__ float h0l[MM];

    int blk = blockIdx.x;
    int b = blk >> 2;
    int q = blk & 3;
    int tid = threadIdx.x;

    for (int p = tid; p < TN; p += 256) Xl[p] = X[b * TN + p];
    for (int p = tid; p < 1024; p += 256) {
        int t = p >> 4, kl = p & 15;
        sUe[p] = Ue_w[t * TT_ + q * 16 + kl];
    }
    if (q == 0 && tid < MM) h0l[tid] = h0[b * MM + tid];
    __syncthreads();

    if (q == 0) {
        float2 bl = ((const float2*)b_lstm)[tid];
        float a0 = bl.x, a1 = bl.y;
        for (int j = 0; j < MM; ++j) {
            float h = h0l[j];
            float2 w = ((const float2*)&U_lstm[j * GG])[tid];
            a0 += h * w.x;
            a1 += h * w.y;
        }
        ((float2*)&ws_hb[b * GG])[tid] = make_float2(a0, a1);
    }

    int kl = tid & 15;
    int k  = q * 16 + kl;
    int ir = tid >> 4;
    float ueb = Ue_b[k];
#pragma unroll
    for (int pass = 0; pass < 6; ++pass) {
        int i = pass * 16 + ir;
        if (i < NN) {
            float acc = ueb;
#pragma unroll 8
            for (int t = 0; t < TT_; ++t)
                acc += Xl[t * NN + i] * sUe[t * 16 + kl];
            ws_U[b * TN + i * 64 + k] = exp2f(acc * SC_);   // eU factor
        }
    }
}

// ---------------- kernel 2: fused pipeline; factored exp2; per-wave early epilogue
__global__ __launch_bounds__(256, 4) void k2_main(
    const float* __restrict__ X, const float* __restrict__ s0,
    const float* __restrict__ W_lstm,
    const float* __restrict__ We_w, const float* __restrict__ We_b,
    const float* __restrict__ ve_w, const float* __restrict__ ve_b,
    const float* __restrict__ ws_hb, const float* __restrict__ ws_U,
    float* __restrict__ out)
{
    __shared__ alignas(16) float sXct[NN * TCH];   // [n][tt] transposed X chunk (648)
    __shared__ float sU[NN * 65];                  // eU factors, padded (5265)
    __shared__ float sHc[TCH * 256];               // [tt][ h | c ] (2048)
    __shared__ float sA[TCH * 65];                 // eA factors, padded (520) — wave-private rows
    __shared__ float sSc[TCH * NN];                // alpha (648) — wave-private rows
    __shared__ float sVe[TT_];

    int blk = blockIdx.x;
    int b  = blk >> 3;
    int tc = blk & 7;
    int t0 = tc * TCH;
    int tid = threadIdx.x;
    int u    = tid & 127;
    int half = tid >> 7;        // tt block: half*4 .. half*4+3
    float veb = ve_b[0];

    // ---- stage: issue all independent global loads up front
    float hb0 = ws_hb[b * GG + u];
    float hb1 = ws_hb[b * GG + 128 + u];
    float hb2 = ws_hb[b * GG + 256 + u];
    float hb3 = ws_hb[b * GG + 384 + u];
    float s0v = s0[b * MM + u];

    for (int p = tid; p < NN * TCH; p += 256) {
        float v = X[b * TN + t0 * NN + p];
        int tt = p / NN, np = p - tt * NN;
        sXct[np * TCH + tt] = v;
    }
    for (int p = tid; p < TN; p += 256) {
        int i = p >> 6, k = p & 63;
        sU[i * 65 + k] = ws_U[b * TN + p];
    }
    if (tid < TT_) sVe[tid] = ve_w[tid];
    __syncthreads();                                  // B1

    // ---- phase 1: gates in registers. thread owns unit u, tts half*4..+3, all 4 gates.
    float acc[4][4];
#pragma unroll
    for (int r = 0; r < 4; ++r) {
        acc[r][0] = hb0; acc[r][1] = hb1; acc[r][2] = hb2; acc[r][3] = hb3;
    }
    {
        const float* Wl = &W_lstm[u];
        for (int n = 0; n < NN; ++n) {
            float w0 = Wl[n * GG];
            float w1 = Wl[n * GG + 128];
            float w2 = Wl[n * GG + 256];
            float w3 = Wl[n * GG + 384];
            float4 xv = *(const float4*)&sXct[n * TCH + 4 * half];
            acc[0][0] += xv.x * w0; acc[0][1] += xv.x * w1; acc[0][2] += xv.x * w2; acc[0][3] += xv.x * w3;
            acc[1][0] += xv.y * w0; acc[1][1] += xv.y * w1; acc[1][2] += xv.y * w2; acc[1][3] += xv.y * w3;
            acc[2][0] += xv.z * w0; acc[2][1] += xv.z * w1; acc[2][2] += xv.z * w2; acc[2][3] += xv.z * w3;
            acc[3][0] += xv.w * w0; acc[3][1] += xv.w * w1; acc[3][2] += xv.w * w2; acc[3][3] += xv.w * w3;
        }
    }
    // ---- activations in registers -> sHc
#pragma unroll
    for (int r = 0; r < 4; ++r) {
        int tt = 4 * half + r;
        float gi = sigmoidf_(acc[r][0]);
        float gf = sigmoidf_(acc[r][1]);
        float gg = fast_tanh(acc[r][2]);
        float go = sigmoidf_(acc[r][3]);
        float c  = gf * s0v + gi * gg;
        float h  = go * fast_tanh(c);
        sHc[tt * 256 + u]       = h;
        sHc[tt * 256 + 128 + u] = c;
    }
    __syncthreads();                                  // B2

    // ---- wave-local from here on. wave wv owns tt = wv and wv+4.
    int wv = tid >> 6;
    int l  = tid & 63;

    // phase 2: eA[tt][k] = exp2(SC*(sum_j hc[tt][j]*We_w[j][k] + We_b[k])), k = l
    {
        float a0 = We_b[l], a1 = a0;
        const float* Wep = &We_w[l];
        for (int j = 0; j < 256; ++j) {
            float w  = Wep[j * TT_];
            a0 += sHc[wv * 256 + j]       * w;
            a1 += sHc[(wv + 4) * 256 + j] * w;
        }
        sA[wv * 65 + l]       = exp2f(a0 * SC_);
        sA[(wv + 4) * 65 + l] = exp2f(a1 * SC_);
    }
    // sumVe via wave reduce (also gives the sA writes time to land)
    float sumVe;
    {
        float sv = sVe[l];
        sumVe = sv;
        for (int d = 32; d >= 1; d >>= 1) sumVe += __shfl_xor(sumVe, d, 64);
    }
    // ensure this wave's sA writes are visible to all its lanes
    asm volatile("s_waitcnt lgkmcnt(0)" ::: "memory");
    __builtin_amdgcn_sched_barrier(0);

    // phase 3 + softmax fused, per owned tt; alpha -> wave-private sSc rows
#pragma unroll
    for (int hh = 0; hh < 2; ++hh) {
        int tt = wv + hh * 4;
        const float* Ar = &sA[tt * 65];
        float sc0, sc1;
        {
            const float* Ur = &sU[l * 65];
            float a2 = 0.f;
#pragma unroll 8
            for (int k = 0; k < TT_; ++k) {
                float e = Ar[k] * Ur[k];                    // exp2(SC*(A+U))
                float r2 = __builtin_amdgcn_rcpf(e + 1.0f);
                a2 = fmaf(sVe[k], r2, a2);
            }
            sc0 = sumVe - 2.0f * a2 + veb;
        }
        bool v2 = (l + 64 < NN);
        if (v2) {
            const float* Ur = &sU[(l + 64) * 65];
            float a2 = 0.f;
#pragma unroll 8
            for (int k = 0; k < TT_; ++k) {
                float e = Ar[k] * Ur[k];
                float r2 = __builtin_amdgcn_rcpf(e + 1.0f);
                a2 = fmaf(sVe[k], r2, a2);
            }
            sc1 = sumVe - 2.0f * a2 + veb;
        } else {
            sc1 = -1e30f;
        }
        // softmax over the 81 scores of row tt
        float mx = fmaxf(sc0, sc1);
        for (int d = 32; d >= 1; d >>= 1) mx = fmaxf(mx, __shfl_xor(mx, d, 64));
        float ea = __expf(sc0 - mx);
        float eb = v2 ? __expf(sc1 - mx) : 0.f;
        float s = ea + eb;
        for (int d = 32; d >= 1; d >>= 1) s += __shfl_xor(s, d, 64);
        float inv = 1.f / s;
        sSc[tt * NN + l] = ea * inv;
        if (v2) sSc[tt * NN + l + 64] = eb * inv;
    }
    // intra-wave: alpha rows written by this wave's lanes, read cross-lane below
    asm volatile("s_waitcnt lgkmcnt(0)" ::: "memory");
    __builtin_amdgcn_sched_barrier(0);

    // ---- phase 4 (per-wave, no barrier): wave wv writes output rows t0+wv and t0+wv+4
    // out[t, b, t2, i] = X[b, t2, i] * alpha[t][i]; f32x4 nt stores.
    {
        const f32x4* Xb4 = (const f32x4*)(X + (size_t)b * TN);
        f32x4* o0 = (f32x4*)out + ((size_t)(t0 + wv)     * BB + b) * (TN / 4);
        f32x4* o1 = (f32x4*)out + ((size_t)(t0 + wv + 4) * BB + b) * (TN / 4);
        const float* al0 = &sSc[wv * NN];
        const float* al1 = &sSc[(wv + 4) * NN];
        int i0 = (4 * l) % NN;
        for (int p = l; p < TN / 4; p += 64) {
            f32x4 x4 = Xb4[p];
            int i1 = i0 + 1; if (i1 >= NN) i1 -= NN;
            int i2 = i1 + 1; if (i2 >= NN) i2 -= NN;
            int i3 = i2 + 1; if (i3 >= NN) i3 -= NN;
            f32x4 oa, ob;
            oa.x = x4.x * al0[i0]; oa.y = x4.y * al0[i1];
            oa.z = x4.z * al0[i2]; oa.w = x4.w * al0[i3];
            ob.x = x4.x * al1[i0]; ob.y = x4.y * al1[i1];
            ob.z = x4.z * al1[i2]; ob.w = x4.w * al1[i3];
            __builtin_nontemporal_store(oa, o0 + p);
            __builtin_nontemporal_store(ob, o1 + p);
            i0 += 13; if (i0 >= NN) i0 -= NN;   // (i0 + 256) mod 81
        }
    }
}

extern "C" void kernel_launch(void* const* d_in, const int* in_sizes, int n_in,
                              void* d_out, int out_size, void* d_ws, size_t ws_size,
                              hipStream_t stream) {
    const float* X      = (const float*)d_in[0];
    const float* h0     = (const float*)d_in[1];
    const float* s0     = (const float*)d_in[2];
    const float* W_lstm = (const float*)d_in[3];
    const float* U_lstm = (const float*)d_in[4];
    const float* b_lstm = (const float*)d_in[5];
    const float* We_w   = (const float*)d_in[6];
    const float* We_b   = (const float*)d_in[7];
    const float* Ue_w   = (const float*)d_in[8];
    const float* Ue_b   = (const float*)d_in[9];
    const float* ve_w   = (const float*)d_in[10];
    const float* ve_b   = (const float*)d_in[11];
    float* out = (float*)d_out;

    float* ws    = (float*)d_ws;
    float* ws_hb = ws;                  // B*512 floats
    float* ws_U  = ws + BB * GG;        // B*5184 floats

    k1_prep<<<BB * 4, 256, 0, stream>>>(X, h0, U_lstm, b_lstm, Ue_w, Ue_b, ws_hb, ws_U);
    k2_main<<<NBLK2, 256, 0, stream>>>(X, s0, W_lstm, We_w, We_b, ve_w, ve_b,
                                       ws_hb, ws_U, out);
}